// Round 11
// baseline (217.081 us; speedup 1.0000x reference)
//
#include <hip/hip_runtime.h>

#define N 4096
#define NB 32      // N / 128

typedef __bf16 bf16;
typedef bf16 bf16x4 __attribute__((ext_vector_type(4)));
typedef bf16 bf16x8 __attribute__((ext_vector_type(8)));
typedef float f32x4 __attribute__((ext_vector_type(4)));

__device__ __host__ __forceinline__ constexpr int tri(int i) { return (i * (i + 1)) >> 1; }

// async global(16B) -> LDS, wave-uniform LDS base + lane*16
__device__ __forceinline__ void async16(const bf16* g, const bf16* l) {
    __builtin_amdgcn_global_load_lds(
        (const __attribute__((address_space(1))) unsigned int*)g,
        (__attribute__((address_space(3))) unsigned int*)l, 16, 0, 0);
}

// ---- fused prepass: A -> tri-compacted bf16 128x128 tiles [m][k],
// B -> tri-compacted TRANSPOSED tiles [n][k]; B global stores coalesced via
// LDS transpose (round 2).
__global__ __launch_bounds__(256) void conv_ab(const float* __restrict__ A,
                                               const float* __restrict__ B,
                                               bf16* __restrict__ Abf,
                                               bf16* __restrict__ Btf) {
    __shared__ __align__(16) bf16 T[128 * 136];    // B-transpose staging, pad 136
    const int x = blockIdx.x, y = blockIdx.y;
    const int tid = threadIdx.x;
    if (y < NB) {
        const int bi = y, bk = x;
        if (bk > bi) return;
        bf16* slot = Abf + (size_t)(tri(bi) + bk) * 16384;
#pragma unroll
        for (int it = 0; it < 8; ++it) {
            const int c = it * 256 + tid;
            const int row = c >> 4, col8 = c & 15;
            const float* src = &A[(size_t)(bi * 128 + row) * N + bk * 128 + col8 * 8];
            f32x4 v0 = *(const f32x4*)src;
            f32x4 v1 = *(const f32x4*)(src + 4);
            bf16x8 h = { (bf16)v0[0], (bf16)v0[1], (bf16)v0[2], (bf16)v0[3],
                         (bf16)v1[0], (bf16)v1[1], (bf16)v1[2], (bf16)v1[3] };
            *(bf16x8*)&slot[row * 128 + col8 * 8] = h;
        }
    } else {
        const int bn = y - NB, bk = x;
        if (bk < bn) return;
        bf16* slot = Btf + (size_t)(tri(bk) + bn) * 16384;
        const int kq = tid >> 5;
        const int n4 = tid & 31;
#pragma unroll
        for (int it = 0; it < 4; ++it) {
            const int kl = it * 32 + kq * 4;
            const float* src = &B[(size_t)(bk * 128 + kl) * N + bn * 128 + n4 * 4];
            f32x4 r0 = *(const f32x4*)(src + 0 * N);
            f32x4 r1 = *(const f32x4*)(src + 1 * N);
            f32x4 r2 = *(const f32x4*)(src + 2 * N);
            f32x4 r3 = *(const f32x4*)(src + 3 * N);
#pragma unroll
            for (int i = 0; i < 4; ++i) {
                bf16x4 h = { (bf16)r0[i], (bf16)r1[i], (bf16)r2[i], (bf16)r3[i] };
                *(bf16x4*)&T[(n4 * 4 + i) * 136 + kl] = h;
            }
        }
        __syncthreads();
#pragma unroll
        for (int it = 0; it < 8; ++it) {
            const int idx = it * 256 + tid;
            const int nn = idx >> 4, k8 = idx & 15;
            *(bf16x8*)&slot[nn * 128 + k8 * 8] = *(const bf16x8*)&T[nn * 136 + k8 * 8];
        }
    }
}

// ---- main: R10 loop VERBATIM (single-buffer 32 KB, async16 x8 -> barrier ->
// 32 MFMA -> barrier; 92 VGPR). Round-11 change: SCHEDULE = R5's balanced
// fine split (S=(d>>3)+1 -> 1000 near-uniform units, <=16 stages,
// longest-first) now that atomics are gone (R10 confirmed atomic RMW was
// degrading the feed; R9/R5's fine-split losses were atomic-confounded).
// 1000 blocks x 32 KB LDS -> entire grid co-resident at ~4-5 blocks/CU;
// model predicts feed ~ residency (R2: L2-hit-rate does NOT set per-stage
// time; m103: same loop, uniform 4/CU -> 13.7 TB/s vs our 7.6 at 2.6/CU).
// Split-piece output: piece 0 stores C directly (plain cached store),
// pieces >=1 write f32 partials to ws (472 slots); reduce_k adds them into
// C. Fallback if ws too small: all pieces atomicAdd (R5 semantics, safe).
__global__ __launch_bounds__(256) void tril_mm_kernel(const bf16* __restrict__ Abf,
                                                      const bf16* __restrict__ Btf,
                                                      float* __restrict__ C,
                                                      float* __restrict__ part) {
    // decode unit id -> (d, bj, cidx); descending d (longest-first).
    // psum accumulates partial slots of skipped d's: (32-d)*(S(d)-1),
    // S(d)-1 == d>>3 exactly.
    int id = blockIdx.x;
    int d = NB - 1, psum = 0;
    for (; d > 0; --d) {
        const int cnt = (NB - d) * ((d >> 3) + 1);
        if (id < cnt) break;
        id -= cnt;
        psum += (NB - d) * (d >> 3);
    }
    const int S = (d >> 3) + 1;
    const int bj = id / S;
    const int cidx = id - bj * S;
    const int bi = bj + d;

    // balanced chunking of [bj, bi] (length L = d+1) into S chunks
    const int L = d + 1;
    const int base = L / S, rem = L - base * S;
    const int kb_start = bj + cidx * base + min(cidx, rem);
    const int kb_end   = kb_start + base + (cidx < rem ? 1 : 0);
    const int triBi = tri(bi);

    __shared__ __align__(16) bf16 As[128 * 64];   // 16 KB
    __shared__ __align__(16) bf16 Bs[128 * 64];   // 16 KB

    const int tid = threadIdx.x;
    const int wave = tid >> 6;
    const int wm = (wave >> 1) * 64;
    const int wn = (wave & 1) * 64;
    const int l15 = tid & 15;
    const int quad = (tid & 63) >> 4;
    const int wbase = tid & ~63;

    // per-lane global chunk offsets for staging (inverse swizzle)
    int goff[4];
#pragma unroll
    for (int t = 0; t < 4; ++t) {
        const int s = t * 256 + tid;
        const int row = s >> 3;
        const int kg = (s & 7) ^ (row & 7);
        goff[t] = row * 128 + kg * 8;
    }
    // fragment LDS chunk indices
    int ach[4][2], bch[4][2];
#pragma unroll
    for (int i = 0; i < 4; ++i)
#pragma unroll
        for (int h = 0; h < 2; ++h) {
            const int m = wm + i * 16 + l15;
            const int n = wn + i * 16 + l15;
            const int kg = h * 4 + quad;
            ach[i][h] = m * 8 + (kg ^ (m & 7));
            bch[i][h] = n * 8 + (kg ^ (n & 7));
        }

    f32x4 acc[4][4] = {};

    for (int kb = kb_start; kb < kb_end; ++kb) {
        const bf16* Ab = Abf + (size_t)(triBi + kb) * 16384;
        const bf16* Bb = Btf + (size_t)(tri(kb) + bj) * 16384;
#pragma unroll
        for (int kk = 0; kk < 128; kk += 64) {
#pragma unroll
            for (int t = 0; t < 4; ++t) {
                async16(Ab + kk + goff[t], &As[(t * 256 + wbase) * 8]);
                async16(Bb + kk + goff[t], &Bs[(t * 256 + wbase) * 8]);
            }
            __syncthreads();
#pragma unroll
            for (int h = 0; h < 2; ++h) {
                bf16x8 af[4], bfr[4];
#pragma unroll
                for (int i = 0; i < 4; ++i) {
                    af[i]  = *(const bf16x8*)&As[ach[i][h] * 8];
                    bfr[i] = *(const bf16x8*)&Bs[bch[i][h] * 8];
                }
#pragma unroll
                for (int i = 0; i < 4; ++i)
#pragma unroll
                    for (int j = 0; j < 4; ++j)
                        acc[i][j] = __builtin_amdgcn_mfma_f32_16x16x32_bf16(af[i], bfr[j], acc[i][j], 0, 0, 0);
            }
            __syncthreads();
        }
    }

    // epilogue: C/D layout col = lane&15, row = quad*4 + v.
    // S==1 (d<=7, incl. diagonal): nontemporal direct store (exact zeros
    // above diagonal). Split piece 0: plain cached store to C (reduce adds
    // the rest later; no race -- other pieces go to private slots). Split
    // pieces >=1: f32 partial to ws slot, or atomicAdd fallback.
    const int row0 = bi * 128, col0 = bj * 128;
    if (S == 1) {
#pragma unroll
        for (int i = 0; i < 4; ++i)
#pragma unroll
            for (int j = 0; j < 4; ++j) {
                const int colg = col0 + wn + j * 16 + l15;
#pragma unroll
                for (int v = 0; v < 4; ++v) {
                    const int rowg = row0 + wm + i * 16 + quad * 4 + v;
                    __builtin_nontemporal_store(acc[i][j][v], &C[(size_t)rowg * N + colg]);
                }
            }
    } else if (part) {
        if (cidx == 0) {
#pragma unroll
            for (int i = 0; i < 4; ++i)
#pragma unroll
                for (int j = 0; j < 4; ++j) {
                    const int colg = col0 + wn + j * 16 + l15;
#pragma unroll
                    for (int v = 0; v < 4; ++v) {
                        const int rowg = row0 + wm + i * 16 + quad * 4 + v;
                        C[(size_t)rowg * N + colg] = acc[i][j][v];
                    }
                }
        } else {
            float* p = part + (size_t)(psum + bj * (S - 1) + (cidx - 1)) * 16384;
#pragma unroll
            for (int i = 0; i < 4; ++i)
#pragma unroll
                for (int j = 0; j < 4; ++j) {
                    const int colt = wn + j * 16 + l15;
#pragma unroll
                    for (int v = 0; v < 4; ++v) {
                        const int rowt = wm + i * 16 + quad * 4 + v;
                        p[rowt * 128 + colt] = acc[i][j][v];
                    }
                }
        }
    } else {
        // no-workspace fallback: ALL pieces atomicAdd onto poison (R5
        // semantics, verified passing).
#pragma unroll
        for (int i = 0; i < 4; ++i)
#pragma unroll
            for (int j = 0; j < 4; ++j) {
                const int colg = col0 + wn + j * 16 + l15;
#pragma unroll
                for (int v = 0; v < 4; ++v) {
                    const int rowg = row0 + wm + i * 16 + quad * 4 + v;
                    atomicAdd(&C[(size_t)rowg * N + colg], acc[i][j][v]);
                }
            }
    }
}

// ---- reduce: one block per split tile (d>=8): C += sum of its S-1 partials.
// Split tiles strictly below the diagonal -> full 128x128 area valid.
__global__ __launch_bounds__(256) void reduce_k(const float* __restrict__ part,
                                                float* __restrict__ C) {
    int t = blockIdx.x, d = NB - 1, pb = 0;
    for (;; --d) {
        const int tc = NB - d;
        if (t < tc) break;
        t -= tc;
        pb += tc * (d >> 3);
    }
    const int bj = t, bi = bj + d;
    const int npart = d >> 3;                       // S-1 in [1,3]
    const float* p0 = part + (size_t)(pb + bj * npart) * 16384;
    const int row0 = bi * 128, col0 = bj * 128;
    const int tid = threadIdx.x;
#pragma unroll
    for (int it = 0; it < 16; ++it) {
        const int idx = (it * 256 + tid) * 4;      // f32x4 granularity
        const int row = idx >> 7, col = idx & 127;
        float* dst = &C[(size_t)(row0 + row) * N + col0 + col];
        f32x4 r = *(const f32x4*)dst;
        for (int p = 0; p < npart; ++p)
            r += *(const f32x4*)&p0[(size_t)p * 16384 + idx];
#pragma unroll
        for (int v = 0; v < 4; ++v)
            __builtin_nontemporal_store(r[v], &dst[v]);
    }
}

extern "C" void kernel_launch(void* const* d_in, const int* in_sizes, int n_in,
                              void* d_out, int out_size, void* d_ws, size_t ws_size,
                              hipStream_t stream) {
    const float* A = (const float*)d_in[0];
    const float* B = (const float*)d_in[1];
    float* C = (float*)d_out;
    bf16* Abf = (bf16*)d_ws;                       // 528 tiles x 32 KB = 16.5 MiB
    bf16* Btf = Abf + (size_t)528 * 16384;         // another 16.5 MiB
    float* part = (float*)(Btf + (size_t)528 * 16384);   // 472 x 64 KB = 29.5 MiB

    const size_t need = (size_t)528 * 2 * 16384 * 2 + (size_t)472 * 16384 * 4;
    const bool use_part = ws_size >= need;

    int units = 0;
    for (int d = 0; d < NB; ++d) units += (NB - d) * ((d >> 3) + 1);  // = 1000

    conv_ab<<<dim3(NB, 2 * NB), dim3(256), 0, stream>>>(A, B, Abf, Btf);
    tril_mm_kernel<<<dim3(units), dim3(256), 0, stream>>>(Abf, Btf, C,
                                                          use_part ? part : nullptr);
    if (use_part)
        reduce_k<<<dim3(300), dim3(256), 0, stream>>>(part, C);
}